// Round 2
// baseline (302.709 us; speedup 1.0000x reference)
//
#include <hip/hip_runtime.h>
#include <hip/hip_bf16.h>

#define B_SZ 4
#define SEQ 8192
#define DIM 512
#define HEADS 8
#define DH 64
#define INNER 512
#define QKV_COLS 1536
#define M_TOT (B_SZ * SEQ)   // 32768
#define BHN (B_SZ * HEADS)   // 32

typedef __bf16 bf16x8 __attribute__((ext_vector_type(8)));
typedef __bf16 bf16x4 __attribute__((ext_vector_type(4)));
typedef float f32x4 __attribute__((ext_vector_type(4)));

__device__ __forceinline__ float elu1(float x) {
    return x > 0.f ? x + 1.f : __expf(x);   // elu(x)+1 = e^x for x<0
}

__device__ __forceinline__ void gl_lds16(const void* g, void* l) {
    __builtin_amdgcn_global_load_lds(
        (const __attribute__((address_space(1))) unsigned int*)g,
        (__attribute__((address_space(3))) unsigned int*)l, 16, 0, 0);
}

// ---------------- K0a: x fp32 -> bf16 ----------------------------------------
__global__ void convert_x(const float* __restrict__ x, __bf16* __restrict__ xb) {
    int id = blockIdx.x * 256 + threadIdx.x;     // 4M float4 chunks
    float4 f = reinterpret_cast<const float4*>(x)[id];
    bf16x4 h = {(__bf16)f.x, (__bf16)f.y, (__bf16)f.z, (__bf16)f.w};
    reinterpret_cast<bf16x4*>(xb)[id] = h;
}

// ---------------- K0b: convert + transpose weights to bf16 B^T layout --------
__global__ void convert_weights(const float* __restrict__ w_qkv,
                                const float* __restrict__ w_out,
                                __bf16* __restrict__ wqkv_t,   // [1536][512]
                                __bf16* __restrict__ wout_t) { // [512][512]
    int id = blockIdx.x * 256 + threadIdx.x;
    if (id < QKV_COLS * DIM) {
        int n = id / DIM, k = id % DIM;
        wqkv_t[id] = (__bf16)w_qkv[k * QKV_COLS + n];
    } else {
        int id2 = id - QKV_COLS * DIM;
        if (id2 < INNER * DIM) {
            int n = id2 / DIM, k = id2 % DIM;
            wout_t[id2] = (__bf16)w_out[k * DIM + n];
        }
    }
}

// ---------------- K1: qkv GEMM, m97 structure, fused elu + LDS-transposed ----
// epilogue. which = q/k/v is uniform per block (n-tile 128 divides 512).
#define TSTR 136   // epilogue transpose stride (272 B = 17*16 -> 16B-aligned rows)
__launch_bounds__(256, 2)
__global__ void gemm_qkv(const __bf16* __restrict__ xb,
                         const __bf16* __restrict__ wqkv_t,
                         __bf16* __restrict__ q_ws,    // [b,h,n,dh]
                         __bf16* __restrict__ kT_ws,   // [b,h,dh,n]
                         __bf16* __restrict__ vT_ws) { // [b,h,dh,n]
    __shared__ __attribute__((aligned(16))) char smem[128 * TSTR * 2]; // 34816 B
    __bf16* As = (__bf16*)smem;              // [128][64] packed, 16 KB
    __bf16* Bs = (__bf16*)(smem + 16384);    // [128][64] packed, 16 KB
    __bf16* T  = (__bf16*)smem;              // [128][TSTR] epilogue transpose

    const int tid = threadIdx.x;
    const int wid = tid >> 6;
    const int lane = tid & 63;
    const int wm = wid >> 1, wn = wid & 1;
    const int lq = lane >> 4, lr = lane & 15;
    const int m0 = blockIdx.x * 128;
    const int n0 = blockIdx.y * 128;
    const int lrow = lane >> 3;              // staging: row within 8-row group
    const int lcol = (lane & 7) * 8;         // staging: k-chunk (8 bf16 = 16 B)

    f32x4 acc[4][4] = {};

    for (int kb = 0; kb < DIM; kb += 64) {
#pragma unroll
        for (int t = 0; t < 4; ++t) {
            int qi = wid * 4 + t;            // instruction index 0..15
            int row = qi * 8 + lrow;
            gl_lds16(&xb[(size_t)(m0 + row) * DIM + kb + lcol], &As[qi * 512]);
            gl_lds16(&wqkv_t[(size_t)(n0 + row) * DIM + kb + lcol], &Bs[qi * 512]);
        }
        __syncthreads();
#pragma unroll
        for (int ks = 0; ks < 2; ++ks) {
            bf16x8 af[4], bfv[4];
#pragma unroll
            for (int i = 0; i < 4; ++i)
                af[i] = *reinterpret_cast<const bf16x8*>(
                    &As[(wm * 64 + i * 16 + lr) * 64 + ks * 32 + lq * 8]);
#pragma unroll
            for (int j = 0; j < 4; ++j)
                bfv[j] = *reinterpret_cast<const bf16x8*>(
                    &Bs[(wn * 64 + j * 16 + lr) * 64 + ks * 32 + lq * 8]);
#pragma unroll
            for (int i = 0; i < 4; ++i)
#pragma unroll
                for (int j = 0; j < 4; ++j)
                    acc[i][j] = __builtin_amdgcn_mfma_f32_16x16x32_bf16(
                        af[i], bfv[j], acc[i][j], 0, 0, 0);
        }
        __syncthreads();
    }

    const int which = n0 / INNER;            // 0=q 1=k 2=v (block-uniform)
    const int n0w = n0 % INNER;
    const int b = m0 / SEQ;
    const int nbase = m0 % SEQ;

    if (which == 0) {
        // T[row][col]: scalar writes with elu, then coalesced [n][dh] stores
#pragma unroll
        for (int i = 0; i < 4; ++i)
#pragma unroll
            for (int j = 0; j < 4; ++j) {
                int col = wn * 64 + j * 16 + lr;
#pragma unroll
                for (int r = 0; r < 4; ++r)
                    T[(wm * 64 + i * 16 + lq * 4 + r) * TSTR + col] =
                        (__bf16)elu1(acc[i][j][r]);
            }
        __syncthreads();
#pragma unroll
        for (int it = 0; it < 8; ++it) {
            int c = tid + it * 256;          // 2048 chunks of 8
            int row = c >> 4, dc = (c & 15) * 8;
            bf16x8 v = *reinterpret_cast<const bf16x8*>(&T[row * TSTR + dc]);
            int col = n0w + dc;
            int h = col >> 6, d = col & 63;
            *reinterpret_cast<bf16x8*>(
                &q_ws[(((size_t)(b * HEADS + h)) * SEQ + nbase + row) * DH + d]) = v;
        }
    } else {
        __bf16* dst = (which == 1) ? kT_ws : vT_ws;
        // T[col][row]: vector 8B writes, then coalesced [dh][n] stores
#pragma unroll
        for (int i = 0; i < 4; ++i)
#pragma unroll
            for (int j = 0; j < 4; ++j) {
                int col = wn * 64 + j * 16 + lr;
                int rowb = wm * 64 + i * 16 + lq * 4;
                bf16x4 h4;
#pragma unroll
                for (int r = 0; r < 4; ++r) {
                    float v = acc[i][j][r];
                    h4[r] = (__bf16)((which == 1) ? elu1(v) : v);
                }
                *reinterpret_cast<bf16x4*>(&T[col * TSTR + rowb]) = h4;
            }
        __syncthreads();
#pragma unroll
        for (int it = 0; it < 8; ++it) {
            int c = tid + it * 256;
            int colIdx = c >> 4, rc = (c & 15) * 8;
            bf16x8 v = *reinterpret_cast<const bf16x8*>(&T[colIdx * TSTR + rc]);
            int gcol = n0w + colIdx;
            int h = gcol >> 6, d = gcol & 63;
            *reinterpret_cast<bf16x8*>(
                &dst[(((size_t)(b * HEADS + h)) * DH + d) * SEQ + nbase + rc]) = v;
        }
    }
}

// ---------------- K2: kv^T[bh][m][d] = sum_n K^T[d][n] * V[n][m] --------------
__launch_bounds__(256, 2)
__global__ void kv_reduce(const __bf16* __restrict__ kT,
                          const __bf16* __restrict__ vT,
                          float* __restrict__ kv_t) {   // [bh][m][d] fp32
    __shared__ __attribute__((aligned(16))) __bf16 Ks[64][136];
    __shared__ __attribute__((aligned(16))) __bf16 Vs[64][136];
    const int tid = threadIdx.x;
    const int wid = tid >> 6;
    const int lane = tid & 63;
    const int lq = lane >> 4, lr = lane & 15;
    const int bh = blockIdx.y;
    const int n0 = blockIdx.x * 512;
    const size_t base = (size_t)bh * DH * SEQ;
    f32x4 acc[4] = {};

    for (int ch = 0; ch < 4; ++ch) {
        int nc = n0 + ch * 128;
#pragma unroll
        for (int t = 0; t < 4; ++t) {
            int c = tid + t * 256;              // 1024 chunks: 64 rows x 16
            int row = c >> 4, kc = (c & 15) * 8;
            *reinterpret_cast<bf16x8*>(&Ks[row][kc]) =
                *reinterpret_cast<const bf16x8*>(&kT[base + (size_t)row * SEQ + nc + kc]);
            *reinterpret_cast<bf16x8*>(&Vs[row][kc]) =
                *reinterpret_cast<const bf16x8*>(&vT[base + (size_t)row * SEQ + nc + kc]);
        }
        __syncthreads();
#pragma unroll
        for (int ks = 0; ks < 4; ++ks) {
            bf16x8 a = *reinterpret_cast<const bf16x8*>(&Ks[wid * 16 + lr][ks * 32 + lq * 8]);
#pragma unroll
            for (int j = 0; j < 4; ++j) {
                bf16x8 b = *reinterpret_cast<const bf16x8*>(&Vs[j * 16 + lr][ks * 32 + lq * 8]);
                acc[j] = __builtin_amdgcn_mfma_f32_16x16x32_bf16(a, b, acc[j], 0, 0, 0);
            }
        }
        __syncthreads();
    }
    float* dst = kv_t + (size_t)bh * DH * DH;
#pragma unroll
    for (int j = 0; j < 4; ++j) {
        int m = j * 16 + lr;
#pragma unroll
        for (int r = 0; r < 4; ++r) {
            int d = wid * 16 + lq * 4 + r;
            atomicAdd(&dst[m * DH + d], acc[j][r]);
        }
    }
}

// ---------------- K3: ksum[bh*64+d] = sum_n K^T[d][n] -------------------------
__global__ void ksum_kernel(const __bf16* __restrict__ kT, float* __restrict__ ksum) {
    const int wid = threadIdx.x >> 6, lane = threadIdx.x & 63;
    const int row = blockIdx.x * 4 + wid;         // 0..2047
    const __bf16* src = kT + (size_t)row * SEQ;
    float s = 0.f;
    for (int i = 0; i < 16; ++i) {
        bf16x8 v = *reinterpret_cast<const bf16x8*>(&src[(i * 64 + lane) * 8]);
#pragma unroll
        for (int j = 0; j < 8; ++j) s += (float)v[j];
    }
#pragma unroll
    for (int off = 32; off > 0; off >>= 1) s += __shfl_down(s, off, 64);
    if (lane == 0) ksum[row] = s;
}

// ---------------- K4: attn[b][n][h*64+m] = z * (q @ kv) -----------------------
__launch_bounds__(256, 2)
__global__ void attn_kernel(const __bf16* __restrict__ q_ws,
                            const float* __restrict__ kv_t,
                            const float* __restrict__ ksum,
                            __bf16* __restrict__ attn) {
    __shared__ __attribute__((aligned(16))) __bf16 Qs[128][72];
    __shared__ __attribute__((aligned(16))) __bf16 KVs[64][72];
    __shared__ float zs[128];
    __shared__ float ks_s[64];
    const int tid = threadIdx.x;
    const int wid = tid >> 6, lane = tid & 63;
    const int lq = lane >> 4, lr = lane & 15;
    const int bh = blockIdx.y;
    const int b = bh >> 3, h = bh & 7;
    const int n0 = blockIdx.x * 128;
    const size_t qbase = ((size_t)bh * SEQ + n0) * DH;

#pragma unroll
    for (int t = 0; t < 4; ++t) {
        int c = tid + t * 256;                    // 128 rows x 8 chunks
        int row = c >> 3, kc = (c & 7) * 8;
        *reinterpret_cast<bf16x8*>(&Qs[row][kc]) =
            *reinterpret_cast<const bf16x8*>(&q_ws[qbase + (size_t)row * DH + kc]);
    }
    const float* kvsrc = kv_t + (size_t)bh * DH * DH;
#pragma unroll
    for (int t = 0; t < 4; ++t) {
        int c = tid + t * 256;                    // 64 rows x 16 float4
        int m = c >> 4, dc = (c & 15) * 4;
        float4 f = *reinterpret_cast<const float4*>(&kvsrc[m * DH + dc]);
        bf16x4 h4 = {(__bf16)f.x, (__bf16)f.y, (__bf16)f.z, (__bf16)f.w};
        *reinterpret_cast<bf16x4*>(&KVs[m][dc]) = h4;
    }
    if (tid < 64) ks_s[tid] = ksum[bh * DH + tid];
    __syncthreads();
    {
        int row = tid >> 1, part = tid & 1;
        float s = 0.f;
#pragma unroll
        for (int j = 0; j < 32; ++j)
            s += (float)Qs[row][part * 32 + j] * ks_s[part * 32 + j];
        s += __shfl_xor(s, 1, 64);
        if (part == 0) zs[row] = 1.f / (s + 1e-6f);
    }
    __syncthreads();

    f32x4 acc[2][4] = {};
#pragma unroll
    for (int ks = 0; ks < 2; ++ks) {
        bf16x8 a0 = *reinterpret_cast<const bf16x8*>(&Qs[wid * 32 + lr][ks * 32 + lq * 8]);
        bf16x8 a1 = *reinterpret_cast<const bf16x8*>(&Qs[wid * 32 + 16 + lr][ks * 32 + lq * 8]);
#pragma unroll
        for (int j = 0; j < 4; ++j) {
            bf16x8 bfr = *reinterpret_cast<const bf16x8*>(&KVs[j * 16 + lr][ks * 32 + lq * 8]);
            acc[0][j] = __builtin_amdgcn_mfma_f32_16x16x32_bf16(a0, bfr, acc[0][j], 0, 0, 0);
            acc[1][j] = __builtin_amdgcn_mfma_f32_16x16x32_bf16(a1, bfr, acc[1][j], 0, 0, 0);
        }
    }
#pragma unroll
    for (int mt = 0; mt < 2; ++mt)
#pragma unroll
        for (int j = 0; j < 4; ++j) {
            int m = j * 16 + lr;
#pragma unroll
            for (int r = 0; r < 4; ++r) {
                int row = wid * 32 + mt * 16 + lq * 4 + r;
                float v = acc[mt][j][r] * zs[row];
                attn[((size_t)(b * SEQ + n0 + row)) * INNER + h * DH + m] = (__bf16)v;
            }
        }
}

// ---------------- K5: out = attn @ w_out + b_out (fp32 out), m97 structure ----
__launch_bounds__(256, 2)
__global__ void gemm_out(const __bf16* __restrict__ attn,
                         const __bf16* __restrict__ wout_t,
                         const float* __restrict__ b_out,
                         float* __restrict__ out) {
    __shared__ __attribute__((aligned(16))) char smem[32768];
    __bf16* As = (__bf16*)smem;              // [128][64] packed
    __bf16* Bs = (__bf16*)(smem + 16384);

    const int tid = threadIdx.x;
    const int wid = tid >> 6;
    const int lane = tid & 63;
    const int wm = wid >> 1, wn = wid & 1;
    const int lq = lane >> 4, lr = lane & 15;
    const int m0 = blockIdx.x * 128;
    const int n0 = blockIdx.y * 128;
    const int lrow = lane >> 3;
    const int lcol = (lane & 7) * 8;

    f32x4 acc[4][4] = {};

    for (int kb = 0; kb < INNER; kb += 64) {
#pragma unroll
        for (int t = 0; t < 4; ++t) {
            int qi = wid * 4 + t;
            int row = qi * 8 + lrow;
            gl_lds16(&attn[(size_t)(m0 + row) * INNER + kb + lcol], &As[qi * 512]);
            gl_lds16(&wout_t[(size_t)(n0 + row) * INNER + kb + lcol], &Bs[qi * 512]);
        }
        __syncthreads();
#pragma unroll
        for (int ks = 0; ks < 2; ++ks) {
            bf16x8 af[4], bfv[4];
#pragma unroll
            for (int i = 0; i < 4; ++i)
                af[i] = *reinterpret_cast<const bf16x8*>(
                    &As[(wm * 64 + i * 16 + lr) * 64 + ks * 32 + lq * 8]);
#pragma unroll
            for (int j = 0; j < 4; ++j)
                bfv[j] = *reinterpret_cast<const bf16x8*>(
                    &Bs[(wn * 64 + j * 16 + lr) * 64 + ks * 32 + lq * 8]);
#pragma unroll
            for (int i = 0; i < 4; ++i)
#pragma unroll
                for (int j = 0; j < 4; ++j)
                    acc[i][j] = __builtin_amdgcn_mfma_f32_16x16x32_bf16(
                        af[i], bfv[j], acc[i][j], 0, 0, 0);
        }
        __syncthreads();
    }

#pragma unroll
    for (int j = 0; j < 4; ++j) {
        int col = n0 + wn * 64 + j * 16 + lr;
        float bias = b_out[col];
#pragma unroll
        for (int i = 0; i < 4; ++i) {
            int row = m0 + wm * 64 + i * 16 + lq * 4;
#pragma unroll
            for (int r = 0; r < 4; ++r)
                out[(size_t)(row + r) * DIM + col] = acc[i][j][r] + bias;
        }
    }
}

// ------------------------------------------------------------------------------
extern "C" void kernel_launch(void* const* d_in, const int* in_sizes, int n_in,
                              void* d_out, int out_size, void* d_ws, size_t ws_size,
                              hipStream_t stream) {
    (void)in_sizes; (void)n_in; (void)out_size; (void)ws_size;
    const float* x     = (const float*)d_in[0];
    const float* w_qkv = (const float*)d_in[1];
    const float* w_out = (const float*)d_in[2];
    const float* b_out = (const float*)d_in[3];
    float* out = (float*)d_out;

    char* ws = (char*)d_ws;
    size_t off = 0;
    auto alloc = [&](size_t bytes) {
        char* p = ws + off;
        off += (bytes + 255) & ~(size_t)255;
        return p;
    };
    // xb (bf16 x) aliases attn: xb dead after gemm_qkv, attn born at attn_kernel
    __bf16* xb     = (__bf16*)alloc((size_t)M_TOT * DIM * 2);    // 33.5 MB
    __bf16* attn   = xb;                                         // alias (same size)
    __bf16* q_ws   = (__bf16*)alloc((size_t)BHN * SEQ * DH * 2);
    __bf16* kT_ws  = (__bf16*)alloc((size_t)BHN * SEQ * DH * 2);
    __bf16* vT_ws  = (__bf16*)alloc((size_t)BHN * SEQ * DH * 2);
    float*  kv_t   = (float*)alloc((size_t)BHN * DH * DH * 4 + (size_t)BHN * DH * 4);
    float*  ksum   = kv_t + (size_t)BHN * DH * DH;
    __bf16* wqkv_t = (__bf16*)alloc((size_t)QKV_COLS * DIM * 2);
    __bf16* wout_t = (__bf16*)alloc((size_t)INNER * DIM * 2);

    hipMemsetAsync(kv_t, 0, (size_t)BHN * DH * DH * 4 + (size_t)BHN * DH * 4, stream);
    convert_x<<<dim3(M_TOT * DIM / 4 / 256), 256, 0, stream>>>(x, xb);
    convert_weights<<<dim3((QKV_COLS * DIM + INNER * DIM) / 256), 256, 0, stream>>>(
        w_qkv, w_out, wqkv_t, wout_t);
    gemm_qkv<<<dim3(M_TOT / 128, QKV_COLS / 128), 256, 0, stream>>>(
        xb, wqkv_t, q_ws, kT_ws, vT_ws);
    kv_reduce<<<dim3(16, BHN), 256, 0, stream>>>(kT_ws, vT_ws, kv_t);
    ksum_kernel<<<dim3(BHN * DH / 4), 256, 0, stream>>>(kT_ws, ksum);
    attn_kernel<<<dim3(SEQ / 128, BHN), 256, 0, stream>>>(q_ws, kv_t, ksum, attn);
    gemm_out<<<dim3(M_TOT / 128, DIM / 128), 256, 0, stream>>>(attn, wout_t, b_out, out);
}

// Round 3
// 266.966 us; speedup vs baseline: 1.1339x; 1.1339x over previous
//
#include <hip/hip_runtime.h>
#include <hip/hip_bf16.h>

#define B_SZ 4
#define SEQ 8192
#define DIM 512
#define HEADS 8
#define DH 64
#define INNER 512
#define QKV_COLS 1536
#define M_TOT (B_SZ * SEQ)   // 32768
#define BHN (B_SZ * HEADS)   // 32

typedef __bf16 bf16x8 __attribute__((ext_vector_type(8)));
typedef __bf16 bf16x4 __attribute__((ext_vector_type(4)));
typedef float f32x4 __attribute__((ext_vector_type(4)));

__device__ __forceinline__ float elu1(float x) {
    return x > 0.f ? x + 1.f : __expf(x);   // elu(x)+1 = e^x for x<0
}

__device__ __forceinline__ void gl_lds16(const void* g, void* l) {
    __builtin_amdgcn_global_load_lds(
        (const __attribute__((address_space(1))) unsigned int*)g,
        (__attribute__((address_space(3))) unsigned int*)l, 16, 0, 0);
}

// ---------------- K0: all conversions in one launch ---------------------------
__global__ void convert_all(const float* __restrict__ x,
                            const float* __restrict__ w_qkv,
                            const float* __restrict__ w_out,
                            __bf16* __restrict__ xb,
                            __bf16* __restrict__ wqkv_t,   // [1536][512]
                            __bf16* __restrict__ wout_t) { // [512][512]
    const int NX = M_TOT * DIM / 4;          // float4 chunks of x
    int id = blockIdx.x * 256 + threadIdx.x;
    if (id < NX) {
        float4 f = reinterpret_cast<const float4*>(x)[id];
        bf16x4 h = {(__bf16)f.x, (__bf16)f.y, (__bf16)f.z, (__bf16)f.w};
        reinterpret_cast<bf16x4*>(xb)[id] = h;
        return;
    }
    int id2 = id - NX;
    if (id2 < QKV_COLS * DIM) {
        int n = id2 / DIM, k = id2 % DIM;
        wqkv_t[id2] = (__bf16)w_qkv[k * QKV_COLS + n];
    } else {
        int id3 = id2 - QKV_COLS * DIM;
        if (id3 < INNER * DIM) {
            int n = id3 / DIM, k = id3 % DIM;
            wout_t[id3] = (__bf16)w_out[k * DIM + n];
        }
    }
}

// ---------------- K1: qkv GEMM, swizzled LDS, fused elu + transposed epilogue -
// LDS chunk swizzle: 16B chunk c of row r stored at slot c ^ (r&7).
#define TSTR 136   // epilogue transpose stride (272 B) -> 16B-aligned rows
__launch_bounds__(256, 2)
__global__ void gemm_qkv(const __bf16* __restrict__ xb,
                         const __bf16* __restrict__ wqkv_t,
                         __bf16* __restrict__ q_ws,    // [b,h,n,dh]
                         __bf16* __restrict__ kT_ws,   // [b,h,dh,n]
                         __bf16* __restrict__ vT_ws) { // [b,h,dh,n]
    __shared__ __attribute__((aligned(16))) char smem[128 * TSTR * 2]; // 34816 B
    __bf16* As = (__bf16*)smem;              // [128][64] packed, 16 KB
    __bf16* Bs = (__bf16*)(smem + 16384);    // [128][64] packed, 16 KB
    __bf16* T  = (__bf16*)smem;              // [128][TSTR] epilogue transpose

    const int tid = threadIdx.x;
    const int wid = tid >> 6;
    const int lane = tid & 63;
    const int wm = wid >> 1, wn = wid & 1;
    const int lq = lane >> 4, lr = lane & 15;
    const int m0 = blockIdx.x * 128;
    const int n0 = blockIdx.y * 128;
    const int lrow = lane >> 3;              // staging: row within 8-row group
    const int lsw  = ((lane & 7) ^ lrow) * 8; // swizzled source chunk (elems)

    f32x4 acc[4][4] = {};

    for (int kb = 0; kb < DIM; kb += 64) {
#pragma unroll
        for (int t = 0; t < 4; ++t) {
            int qi = wid * 4 + t;            // instruction index 0..15
            int row = qi * 8 + lrow;
            gl_lds16(&xb[(size_t)(m0 + row) * DIM + kb + lsw], &As[qi * 512]);
            gl_lds16(&wqkv_t[(size_t)(n0 + row) * DIM + kb + lsw], &Bs[qi * 512]);
        }
        __syncthreads();
#pragma unroll
        for (int ks = 0; ks < 2; ++ks) {
            const int csw = ((ks * 4 + lq) ^ (lr & 7)) * 8;  // swizzled read slot
            bf16x8 af[4], bfv[4];
#pragma unroll
            for (int i = 0; i < 4; ++i)
                af[i] = *reinterpret_cast<const bf16x8*>(
                    &As[(wm * 64 + i * 16 + lr) * 64 + csw]);
#pragma unroll
            for (int j = 0; j < 4; ++j)
                bfv[j] = *reinterpret_cast<const bf16x8*>(
                    &Bs[(wn * 64 + j * 16 + lr) * 64 + csw]);
#pragma unroll
            for (int i = 0; i < 4; ++i)
#pragma unroll
                for (int j = 0; j < 4; ++j)
                    acc[i][j] = __builtin_amdgcn_mfma_f32_16x16x32_bf16(
                        af[i], bfv[j], acc[i][j], 0, 0, 0);
        }
        __syncthreads();
    }

    const int which = n0 / INNER;            // 0=q 1=k 2=v (block-uniform)
    const int n0w = n0 % INNER;
    const int b = m0 / SEQ;
    const int nbase = m0 % SEQ;

    if (which == 0) {
        // T[row][col]: scalar writes with elu, then coalesced [n][dh] stores
#pragma unroll
        for (int i = 0; i < 4; ++i)
#pragma unroll
            for (int j = 0; j < 4; ++j) {
                int col = wn * 64 + j * 16 + lr;
#pragma unroll
                for (int r = 0; r < 4; ++r)
                    T[(wm * 64 + i * 16 + lq * 4 + r) * TSTR + col] =
                        (__bf16)elu1(acc[i][j][r]);
            }
        __syncthreads();
#pragma unroll
        for (int it = 0; it < 8; ++it) {
            int c = tid + it * 256;          // 2048 chunks of 8
            int row = c >> 4, dc = (c & 15) * 8;
            bf16x8 v = *reinterpret_cast<const bf16x8*>(&T[row * TSTR + dc]);
            int col = n0w + dc;
            int h = col >> 6, d = col & 63;
            *reinterpret_cast<bf16x8*>(
                &q_ws[(((size_t)(b * HEADS + h)) * SEQ + nbase + row) * DH + d]) = v;
        }
    } else {
        __bf16* dst = (which == 1) ? kT_ws : vT_ws;
        // T[col][row]: vector 8B writes, then coalesced [dh][n] stores
#pragma unroll
        for (int i = 0; i < 4; ++i)
#pragma unroll
            for (int j = 0; j < 4; ++j) {
                int col = wn * 64 + j * 16 + lr;
                int rowb = wm * 64 + i * 16 + lq * 4;
                bf16x4 h4;
#pragma unroll
                for (int r = 0; r < 4; ++r) {
                    float v = acc[i][j][r];
                    h4[r] = (__bf16)((which == 1) ? elu1(v) : v);
                }
                *reinterpret_cast<bf16x4*>(&T[col * TSTR + rowb]) = h4;
            }
        __syncthreads();
#pragma unroll
        for (int it = 0; it < 8; ++it) {
            int c = tid + it * 256;
            int colIdx = c >> 4, rc = (c & 15) * 8;
            bf16x8 v = *reinterpret_cast<const bf16x8*>(&T[colIdx * TSTR + rc]);
            int gcol = n0w + colIdx;
            int h = gcol >> 6, d = gcol & 63;
            *reinterpret_cast<bf16x8*>(
                &dst[(((size_t)(b * HEADS + h)) * DH + d) * SEQ + nbase + rc]) = v;
        }
    }
}

// ---------------- K2: kv^T[bh][m][d] = sum_n K^T[d][n]*V[n][m]; + ksum fused --
__launch_bounds__(256, 2)
__global__ void kv_reduce(const __bf16* __restrict__ kT,
                          const __bf16* __restrict__ vT,
                          float* __restrict__ kv_t,     // [bh][m][d] fp32
                          float* __restrict__ ksum) {   // [bh][d]
    __shared__ __attribute__((aligned(16))) __bf16 Ks[64][136];
    __shared__ __attribute__((aligned(16))) __bf16 Vs[64][136];
    const int tid = threadIdx.x;
    const int wid = tid >> 6;
    const int lane = tid & 63;
    const int lq = lane >> 4, lr = lane & 15;
    const int bh = blockIdx.y;
    const int n0 = blockIdx.x * 512;
    const size_t base = (size_t)bh * DH * SEQ;
    f32x4 acc[4] = {};
    f32x4 acc1 = {};
    bf16x8 ones8;
#pragma unroll
    for (int e = 0; e < 8; ++e) ones8[e] = (__bf16)1.f;

    for (int ch = 0; ch < 4; ++ch) {
        int nc = n0 + ch * 128;
#pragma unroll
        for (int t = 0; t < 4; ++t) {
            int c = tid + t * 256;              // 1024 chunks: 64 rows x 16
            int row = c >> 4, kc = (c & 15) * 8;
            *reinterpret_cast<bf16x8*>(&Ks[row][kc]) =
                *reinterpret_cast<const bf16x8*>(&kT[base + (size_t)row * SEQ + nc + kc]);
            *reinterpret_cast<bf16x8*>(&Vs[row][kc]) =
                *reinterpret_cast<const bf16x8*>(&vT[base + (size_t)row * SEQ + nc + kc]);
        }
        __syncthreads();
#pragma unroll
        for (int ks = 0; ks < 4; ++ks) {
            bf16x8 a = *reinterpret_cast<const bf16x8*>(&Ks[wid * 16 + lr][ks * 32 + lq * 8]);
            acc1 = __builtin_amdgcn_mfma_f32_16x16x32_bf16(a, ones8, acc1, 0, 0, 0);
#pragma unroll
            for (int j = 0; j < 4; ++j) {
                bf16x8 b = *reinterpret_cast<const bf16x8*>(&Vs[j * 16 + lr][ks * 32 + lq * 8]);
                acc[j] = __builtin_amdgcn_mfma_f32_16x16x32_bf16(a, b, acc[j], 0, 0, 0);
            }
        }
        __syncthreads();
    }
    float* dst = kv_t + (size_t)bh * DH * DH;
#pragma unroll
    for (int j = 0; j < 4; ++j) {
        int m = j * 16 + lr;
#pragma unroll
        for (int r = 0; r < 4; ++r) {
            int d = wid * 16 + lq * 4 + r;
            atomicAdd(&dst[m * DH + d], acc[j][r]);
        }
    }
    if (lr == 0) {
#pragma unroll
        for (int r = 0; r < 4; ++r)
            atomicAdd(&ksum[bh * DH + wid * 16 + lq * 4 + r], acc1[r]);
    }
}

// ---------------- K3: attn[b][n][h*64+m] = z * (q @ kv), vectorized stores ----
__launch_bounds__(256, 2)
__global__ void attn_kernel(const __bf16* __restrict__ q_ws,
                            const float* __restrict__ kv_t,
                            const float* __restrict__ ksum,
                            __bf16* __restrict__ attn) {
    __shared__ __attribute__((aligned(16))) __bf16 Qs[128][72];
    __shared__ __attribute__((aligned(16))) __bf16 KVs[64][72];
    __shared__ float zs[128];
    __shared__ float ks_s[64];
    const int tid = threadIdx.x;
    const int wid = tid >> 6, lane = tid & 63;
    const int lq = lane >> 4, lr = lane & 15;
    const int bh = blockIdx.y;
    const int b = bh >> 3, h = bh & 7;
    const int n0 = blockIdx.x * 128;
    const size_t qbase = ((size_t)bh * SEQ + n0) * DH;

#pragma unroll
    for (int t = 0; t < 4; ++t) {
        int c = tid + t * 256;                    // 128 rows x 8 chunks
        int row = c >> 3, kc = (c & 7) * 8;
        *reinterpret_cast<bf16x8*>(&Qs[row][kc]) =
            *reinterpret_cast<const bf16x8*>(&q_ws[qbase + (size_t)row * DH + kc]);
    }
    const float* kvsrc = kv_t + (size_t)bh * DH * DH;
#pragma unroll
    for (int t = 0; t < 4; ++t) {
        int c = tid + t * 256;                    // 64 rows x 16 float4
        int m = c >> 4, dc = (c & 15) * 4;
        float4 f = *reinterpret_cast<const float4*>(&kvsrc[m * DH + dc]);
        bf16x4 h4 = {(__bf16)f.x, (__bf16)f.y, (__bf16)f.z, (__bf16)f.w};
        *reinterpret_cast<bf16x4*>(&KVs[m][dc]) = h4;
    }
    if (tid < 64) ks_s[tid] = ksum[bh * DH + tid];
    __syncthreads();
    {
        int row = tid >> 1, part = tid & 1;
        float s = 0.f;
#pragma unroll
        for (int j = 0; j < 32; ++j)
            s += (float)Qs[row][part * 32 + j] * ks_s[part * 32 + j];
        s += __shfl_xor(s, 1, 64);
        if (part == 0) zs[row] = 1.f / (s + 1e-6f);
    }
    __syncthreads();

    f32x4 acc[2][4] = {};
#pragma unroll
    for (int ks = 0; ks < 2; ++ks) {
        bf16x8 a0 = *reinterpret_cast<const bf16x8*>(&Qs[wid * 32 + lr][ks * 32 + lq * 8]);
        bf16x8 a1 = *reinterpret_cast<const bf16x8*>(&Qs[wid * 32 + 16 + lr][ks * 32 + lq * 8]);
#pragma unroll
        for (int j = 0; j < 4; ++j) {
            bf16x8 bfr = *reinterpret_cast<const bf16x8*>(&KVs[j * 16 + lr][ks * 32 + lq * 8]);
            acc[0][j] = __builtin_amdgcn_mfma_f32_16x16x32_bf16(a0, bfr, acc[0][j], 0, 0, 0);
            acc[1][j] = __builtin_amdgcn_mfma_f32_16x16x32_bf16(a1, bfr, acc[1][j], 0, 0, 0);
        }
    }
    // transpose through LDS (reuse Qs) for coalesced bf16x8 stores
    __syncthreads();
#pragma unroll
    for (int mt = 0; mt < 2; ++mt)
#pragma unroll
        for (int j = 0; j < 4; ++j) {
            int m = j * 16 + lr;
#pragma unroll
            for (int r = 0; r < 4; ++r) {
                int row = wid * 32 + mt * 16 + lq * 4 + r;
                Qs[row][m] = (__bf16)(acc[mt][j][r] * zs[row]);
            }
        }
    __syncthreads();
#pragma unroll
    for (int it = 0; it < 4; ++it) {
        int c = tid + it * 256;                   // 1024 chunks: 128 rows x 8
        int row = c >> 3, mc = (c & 7) * 8;
        bf16x8 v = *reinterpret_cast<const bf16x8*>(&Qs[row][mc]);
        *reinterpret_cast<bf16x8*>(
            &attn[((size_t)(b * SEQ + n0 + row)) * INNER + h * DH + mc]) = v;
    }
}

// ---------------- K4: out = attn @ w_out + b_out (fp32 out), swizzled LDS -----
__launch_bounds__(256, 2)
__global__ void gemm_out(const __bf16* __restrict__ attn,
                         const __bf16* __restrict__ wout_t,
                         const float* __restrict__ b_out,
                         float* __restrict__ out) {
    __shared__ __attribute__((aligned(16))) char smem[32768];
    __bf16* As = (__bf16*)smem;              // [128][64] packed
    __bf16* Bs = (__bf16*)(smem + 16384);

    const int tid = threadIdx.x;
    const int wid = tid >> 6;
    const int lane = tid & 63;
    const int wm = wid >> 1, wn = wid & 1;
    const int lq = lane >> 4, lr = lane & 15;
    const int m0 = blockIdx.x * 128;
    const int n0 = blockIdx.y * 128;
    const int lrow = lane >> 3;
    const int lsw  = ((lane & 7) ^ lrow) * 8;

    f32x4 acc[4][4] = {};

    for (int kb = 0; kb < INNER; kb += 64) {
#pragma unroll
        for (int t = 0; t < 4; ++t) {
            int qi = wid * 4 + t;
            int row = qi * 8 + lrow;
            gl_lds16(&attn[(size_t)(m0 + row) * INNER + kb + lsw], &As[qi * 512]);
            gl_lds16(&wout_t[(size_t)(n0 + row) * INNER + kb + lsw], &Bs[qi * 512]);
        }
        __syncthreads();
#pragma unroll
        for (int ks = 0; ks < 2; ++ks) {
            const int csw = ((ks * 4 + lq) ^ (lr & 7)) * 8;
            bf16x8 af[4], bfv[4];
#pragma unroll
            for (int i = 0; i < 4; ++i)
                af[i] = *reinterpret_cast<const bf16x8*>(
                    &As[(wm * 64 + i * 16 + lr) * 64 + csw]);
#pragma unroll
            for (int j = 0; j < 4; ++j)
                bfv[j] = *reinterpret_cast<const bf16x8*>(
                    &Bs[(wn * 64 + j * 16 + lr) * 64 + csw]);
#pragma unroll
            for (int i = 0; i < 4; ++i)
#pragma unroll
                for (int j = 0; j < 4; ++j)
                    acc[i][j] = __builtin_amdgcn_mfma_f32_16x16x32_bf16(
                        af[i], bfv[j], acc[i][j], 0, 0, 0);
        }
        __syncthreads();
    }

#pragma unroll
    for (int j = 0; j < 4; ++j) {
        int col = n0 + wn * 64 + j * 16 + lr;
        float bias = b_out[col];
#pragma unroll
        for (int i = 0; i < 4; ++i) {
            int row = m0 + wm * 64 + i * 16 + lq * 4;
#pragma unroll
            for (int r = 0; r < 4; ++r)
                out[(size_t)(row + r) * DIM + col] = acc[i][j][r] + bias;
        }
    }
}

// ------------------------------------------------------------------------------
extern "C" void kernel_launch(void* const* d_in, const int* in_sizes, int n_in,
                              void* d_out, int out_size, void* d_ws, size_t ws_size,
                              hipStream_t stream) {
    (void)in_sizes; (void)n_in; (void)out_size; (void)ws_size;
    const float* x     = (const float*)d_in[0];
    const float* w_qkv = (const float*)d_in[1];
    const float* w_out = (const float*)d_in[2];
    const float* b_out = (const float*)d_in[3];
    float* out = (float*)d_out;

    char* ws = (char*)d_ws;
    size_t off = 0;
    auto alloc = [&](size_t bytes) {
        char* p = ws + off;
        off += (bytes + 255) & ~(size_t)255;
        return p;
    };
    // xb (bf16 x) aliases attn: xb dead after gemm_qkv, attn born at attn_kernel
    __bf16* xb     = (__bf16*)alloc((size_t)M_TOT * DIM * 2);    // 33.5 MB
    __bf16* attn   = xb;                                         // alias (same size)
    __bf16* q_ws   = (__bf16*)alloc((size_t)BHN * SEQ * DH * 2);
    __bf16* kT_ws  = (__bf16*)alloc((size_t)BHN * SEQ * DH * 2);
    __bf16* vT_ws  = (__bf16*)alloc((size_t)BHN * SEQ * DH * 2);
    float*  kv_t   = (float*)alloc((size_t)BHN * DH * DH * 4 + (size_t)BHN * DH * 4);
    float*  ksum   = kv_t + (size_t)BHN * DH * DH;
    __bf16* wqkv_t = (__bf16*)alloc((size_t)QKV_COLS * DIM * 2);
    __bf16* wout_t = (__bf16*)alloc((size_t)INNER * DIM * 2);

    hipMemsetAsync(kv_t, 0, (size_t)BHN * DH * DH * 4 + (size_t)BHN * DH * 4, stream);
    convert_all<<<dim3(M_TOT * DIM / 4 / 256 + (QKV_COLS * DIM + INNER * DIM) / 256),
                  256, 0, stream>>>(x, w_qkv, w_out, xb, wqkv_t, wout_t);
    gemm_qkv<<<dim3(M_TOT / 128, QKV_COLS / 128), 256, 0, stream>>>(
        xb, wqkv_t, q_ws, kT_ws, vT_ws);
    kv_reduce<<<dim3(16, BHN), 256, 0, stream>>>(kT_ws, vT_ws, kv_t, ksum);
    attn_kernel<<<dim3(SEQ / 128, BHN), 256, 0, stream>>>(q_ws, kv_t, ksum, attn);
    gemm_out<<<dim3(M_TOT / 128, DIM / 128), 256, 0, stream>>>(attn, wout_t, b_out, out);
}